// Round 1
// 148.106 us; speedup vs baseline: 1.0553x; 1.0553x over previous
//
#include <hip/hip_runtime.h>

typedef __bf16 bf16;
typedef __bf16 bf16x8 __attribute__((ext_vector_type(8)));
typedef float  f32x4  __attribute__((ext_vector_type(4)));

#define T_SEQ   2048
#define D_HEAD  64
#define NH      16
#define BH      32
#define C_EMB   1024
#define WS_STRIDE (BH * T_SEQ * D_HEAD)   // 4,194,304 elems per plane
#define XN (4096 * 1024)
#define WN (3072 * 1024)
#define WS_NEEDED ((size_t)(3 * WS_STRIDE + XN + WN) * 2)
#define CVT_GRID 3584

__device__ __forceinline__ bf16x8 cvt8(float4 a, float4 b) {
    bf16x8 r;
    r[0] = (__bf16)a.x; r[1] = (__bf16)a.y; r[2] = (__bf16)a.z; r[3] = (__bf16)a.w;
    r[4] = (__bf16)b.x; r[5] = (__bf16)b.y; r[6] = (__bf16)b.z; r[7] = (__bf16)b.w;
    return r;
}

__device__ __forceinline__ void gl_lds16(const bf16* g, bf16* l) {
    __builtin_amdgcn_global_load_lds(
        (const __attribute__((address_space(1))) unsigned int*)g,
        (__attribute__((address_space(3))) unsigned int*)l,
        16, 0, 0);
}

__device__ __forceinline__ unsigned pack_bf16(float a, float b) {
    union { __bf16 h[2]; unsigned u; } pk;
    pk.h[0] = (__bf16)a; pk.h[1] = (__bf16)b;
    return pk.u;
}

// ---------------------------------------------------------------------------
// Kernel 0: fp32 -> bf16 convert of x and W.
// ---------------------------------------------------------------------------
__global__ __launch_bounds__(256) void cvt_bf16(
    const float* __restrict__ x, const float* __restrict__ W,
    bf16* __restrict__ xb, bf16* __restrict__ wb)
{
    const int t = blockIdx.x * 256 + threadIdx.x;   // 917504 threads
    const float* src; bf16* dst; int base;
    if (t < XN / 8) { src = x; dst = xb; base = t * 8; }
    else           { src = W; dst = wb; base = (t - XN / 8) * 8; }
    float4 a = *(const float4*)(src + base);
    float4 b = *(const float4*)(src + base + 4);
    *(bf16x8*)(dst + base) = cvt8(a, b);
}

// ---------------------------------------------------------------------------
// Kernel 1: qkv = xb @ wb^T + b.  256x256 tile, BK=64, 8 waves (2Mx4N),
// 8-phase double-buffered pipeline (T3+T4): each K-tile = 4 quadrant phases
// of 16 MFMA; staging global_load_lds lands in quarter-regions that died in
// an earlier phase; s_waitcnt vmcnt(8) once per K-tile (never 0 in loop).
// T2 XOR-swizzled staging (pre-swizzled global source, linear LDS dest),
// T5 setprio around MFMA clusters, T1 bijective XCD swizzle (192%8==0).
// LDS 128 KiB: A0|A1|B0|B1, each 256x64 bf16 region-major:
//   A lds_row = qi*128 + (m>>7)*64 + (m&63)   (qi = (m>>6)&1)
//   B lds_row = qj*128 + (n>>6)*32 + (n&31)   (qj = (n>>5)&1)
// Epilogue: per-wave 128x64 transpose through private 16 KiB LDS slice;
// q plane pre-scaled by 0.125; v plane written transposed vt[bh][d][t].
// ---------------------------------------------------------------------------
#define LDA(d, qi) {                                                          \
    const bf16* abase_ = Sh + (d)*16384 + (qi)*8192 + (wm*64 + l15)*64;       \
    _Pragma("unroll")                                                         \
    for (int ii_ = 0; ii_ < 4; ii_++) {                                       \
        _Pragma("unroll")                                                     \
        for (int dk_ = 0; dk_ < 2; dk_++)                                     \
            aF[ii_][dk_] = *(const bf16x8*)(abase_ + ii_*1024                 \
                                            + (((dk_*4 + l4) ^ k7) * 8));     \
    }                                                                         \
}

#define LDB(d, qj, bFv) {                                                     \
    const bf16* bbase_ = Sh + 32768 + (d)*16384 + (qj)*8192                   \
                         + (wn*32 + l15)*64;                                  \
    _Pragma("unroll")                                                         \
    for (int jj_ = 0; jj_ < 2; jj_++) {                                       \
        _Pragma("unroll")                                                     \
        for (int dk_ = 0; dk_ < 2; dk_++)                                     \
            bFv[jj_][dk_] = *(const bf16x8*)(bbase_ + jj_*1024                \
                                             + (((dk_*4 + l4) ^ k7) * 8));    \
    }                                                                         \
}

#define STA(d, qi, s, ko) gl_lds16(                                           \
    aSrc + (size_t)((qi)*64 + (s)*128) * 1024 + (ko),                         \
    Sh + (d)*16384 + (qi)*8192 + (s)*4096 + w*512)

#define STB(d, qj, s, ko) gl_lds16(                                           \
    bSrc + (size_t)((s)*128 + (qj)*32) * 1024 + (ko),                         \
    Sh + 32768 + (d)*16384 + (qj)*8192 + (s)*4096 + w*512)

#define MMAQ(qi, qj, bFv) {                                                   \
    __builtin_amdgcn_s_setprio(1);                                            \
    _Pragma("unroll")                                                         \
    for (int dk_ = 0; dk_ < 2; dk_++) {                                       \
        _Pragma("unroll")                                                     \
        for (int ii_ = 0; ii_ < 4; ii_++) {                                   \
            _Pragma("unroll")                                                 \
            for (int jj_ = 0; jj_ < 2; jj_++)                                 \
                acc[(qi)*4 + ii_][(qj)*2 + jj_] =                             \
                    __builtin_amdgcn_mfma_f32_16x16x32_bf16(                  \
                        aF[ii_][dk_], bFv[jj_][dk_],                          \
                        acc[(qi)*4 + ii_][(qj)*2 + jj_], 0, 0, 0);            \
        }                                                                     \
    }                                                                         \
    __builtin_amdgcn_s_setprio(0);                                            \
}

#define BAR   __builtin_amdgcn_s_barrier()
#define LGKM0 asm volatile("s_waitcnt lgkmcnt(0)" ::: "memory")

// One K-tile (4 phases) on buffer d, staging next-next tile at k-offset sk.
// Region deaths (register-cached frags): P0 kills Aq0+Bq0, P1 kills Bq1,
// P2 kills Aq1 -> stages issued one phase after death, after the barrier.
#define HALF(d, sk)                                                           \
    /* P0 */                                                                  \
    LDA(d, 0) LDB(d, 0, bF0)                                                  \
    BAR; LGKM0;                                                               \
    MMAQ(0, 0, bF0)                                                           \
    BAR;                                                                      \
    /* P1 */                                                                  \
    LDB(d, 1, bF1)                                                            \
    STA(d, 0, 0, sk); STA(d, 0, 1, sk); STB(d, 0, 0, sk); STB(d, 0, 1, sk);   \
    BAR; LGKM0;                                                               \
    MMAQ(0, 1, bF1)                                                           \
    BAR;                                                                      \
    /* P2 */                                                                  \
    LDA(d, 1)                                                                 \
    STB(d, 1, 0, sk); STB(d, 1, 1, sk);                                       \
    BAR; LGKM0;                                                               \
    MMAQ(1, 0, bF0)                                                           \
    BAR;                                                                      \
    /* P3 */                                                                  \
    STA(d, 1, 0, sk); STA(d, 1, 1, sk);                                       \
    BAR;                                                                      \
    MMAQ(1, 1, bF1)                                                           \
    asm volatile("s_waitcnt vmcnt(8)" ::: "memory");                          \
    BAR;

__global__ __launch_bounds__(512, 2) void qkv_gemm3(
    const bf16* __restrict__ xb, const bf16* __restrict__ wb,
    const float* __restrict__ bias, bf16* __restrict__ ws)
{
    __shared__ bf16 Sh[65536];   // 128 KiB

    const int tid  = threadIdx.x;
    const int lane = tid & 63;
    const int w    = tid >> 6;            // 0..7
    const int wm   = w >> 2, wn = w & 3;  // 2x4 wave grid
    const int l15  = lane & 15, l4 = lane >> 4;
    const int k7   = l15 & 7;
    const int l8   = lane >> 3;           // staging row-in-wave
    const int csw  = (lane & 7) ^ l8;     // pre-swizzled source chunk

    const int swz = (blockIdx.x & 7) * 24 + (blockIdx.x >> 3);  // T1, bijective
    const int bm  = swz / 12, bn = swz % 12;

    const bf16* aSrc = xb + (size_t)(bm * 256 + w * 8 + l8) * 1024 + csw * 8;
    const bf16* bSrc = wb + (size_t)(bn * 256 + (w >> 2) * 64 + (w & 3) * 8 + l8) * 1024
                          + csw * 8;

    f32x4 acc[8][4];
#pragma unroll
    for (int i = 0; i < 8; i++)
#pragma unroll
        for (int j = 0; j < 4; j++) acc[i][j] = (f32x4){0.f, 0.f, 0.f, 0.f};

    bf16x8 aF[4][2], bF0[2][2], bF1[2][2];

    // ---- prologue: stage tile0 -> buf0, tile1 -> buf1 (8 loads each) ----
    STA(0,0,0,0);  STA(0,0,1,0);  STB(0,0,0,0);  STB(0,0,1,0);
    STB(0,1,0,0);  STB(0,1,1,0);  STA(0,1,0,0);  STA(0,1,1,0);
    STA(1,0,0,64); STA(1,0,1,64); STB(1,0,0,64); STB(1,0,1,64);
    STB(1,1,0,64); STB(1,1,1,64); STA(1,1,0,64); STA(1,1,1,64);
    asm volatile("s_waitcnt vmcnt(8)" ::: "memory");   // tile0 landed
    BAR;

    // ---- main loop: 8 iterations x 2 K-tiles (K=1024, BK=64) ----
    for (int it = 0; it < 8; ++it) {
        const int sk0 = (it < 7 ? (2 * it + 2) : 15) * 64;  // clamp: re-stage
        const int sk1 = (it < 7 ? (2 * it + 3) : 15) * 64;  // tile15 harmlessly
        HALF(0, sk0)
        HALF(1, sk1)
    }
    asm volatile("s_waitcnt vmcnt(0)" ::: "memory");   // drain garbage stages
    BAR;                                               // LDS now reusable

    // ---- epilogue: +bias (+0.125 for q); per-wave LDS transpose ----
    float bv[4];
#pragma unroll
    for (int j = 0; j < 4; j++) bv[j] = bias[bn * 256 + wn * 64 + j * 16 + l15];

    const int which = bn >> 2;             // 0=q, 1=k, 2=v (block-uniform)
    const int h     = (bn & 3) * 4 + wn;   // head (wave-uniform)
    const int bi    = bm >> 3;             // batch (block-uniform)
    const int tBase = (bm & 7) * 256 + wm * 128;
    const float qs  = (which == 0) ? 0.125f : 1.0f;
    bf16* Wl = Sh + w * 8192;              // private 16 KiB slice

    if (which < 2) {
#pragma unroll
        for (int i = 0; i < 8; i++)
#pragma unroll
            for (int j = 0; j < 4; j++)
#pragma unroll
                for (int r = 0; r < 4; r++) {
                    const int lm = i * 16 + l4 * 4 + r;     // 0..127 (t-local)
                    const int dd = j * 16 + l15;            // 0..63  (d)
                    const int cp = (dd >> 3) ^ (lm & 7);
                    Wl[lm * 64 + cp * 8 + (dd & 7)] =
                        (__bf16)((acc[i][j][r] + bv[j]) * qs);
                }
#pragma unroll
        for (int e = 0; e < 16; e++) {
            const int lm = e * 8 + l8;
            const int c  = lane & 7;
            bf16x8 v8 = *(const bf16x8*)&Wl[lm * 64 + ((c ^ (lm & 7)) * 8)];
            const int t = tBase + lm;
            *(bf16x8*)&ws[(size_t)which * WS_STRIDE
                          + ((size_t)(bi * NH + h) * T_SEQ + t) * D_HEAD + c * 8] = v8;
        }
    } else {
#pragma unroll
        for (int i = 0; i < 8; i++)
#pragma unroll
            for (int j = 0; j < 4; j++) {
                const int dd = j * 16 + l15;
#pragma unroll
                for (int p = 0; p < 2; p++) {
                    const int lm = i * 16 + l4 * 4 + 2 * p;
                    const int ch = lm >> 3;                 // 0..15
                    const int cp = (ch & 8) | ((ch & 7) ^ (dd & 7));
                    *(unsigned*)&Wl[dd * 128 + cp * 8 + (lm & 7)] =
                        pack_bf16(acc[i][j][2 * p] + bv[j],
                                  acc[i][j][2 * p + 1] + bv[j]);
                }
            }
        bf16* vt = ws + 2 * (size_t)WS_STRIDE;
#pragma unroll
        for (int e = 0; e < 16; e++) {
            const int dd = e * 4 + l4;
            const int c  = l15;
            const int cp = (c & 8) | ((c & 7) ^ (dd & 7));
            bf16x8 v8 = *(const bf16x8*)&Wl[dd * 128 + cp * 8];
            *(bf16x8*)&vt[((size_t)(bi * NH + h) * D_HEAD + dd) * T_SEQ
                          + tBase + c * 8] = v8;
        }
    }
}

// ---------------------------------------------------------------------------
// Kernel 1 fallback (ws too small): register-convert GEMM, scalar epilogue.
// ---------------------------------------------------------------------------
__global__ __launch_bounds__(256) void qkv_gemm(
    const float* __restrict__ x, const float* __restrict__ W,
    const float* __restrict__ bias, bf16* __restrict__ ws)
{
    __shared__ bf16 As[128 * 40];
    __shared__ bf16 Bs[128 * 40];

    const int tid  = threadIdx.x;
    const int lane = tid & 63;
    const int w    = tid >> 6;
    const int wm   = w >> 1, wn = w & 1;
    const int l15  = lane & 15, l4 = lane >> 4;
    const int bm   = blockIdx.x / 24, bn = blockIdx.x % 24;

    const int srow = tid >> 1;
    const int scol = (tid & 1) * 16;
    const float* xg = x + (size_t)(bm * 128 + srow) * 1024 + scol;
    const float* wg = W + (size_t)(bn * 128 + srow) * 1024 + scol;
    bf16* asw = &As[srow * 40 + scol];
    bf16* bsw = &Bs[srow * 40 + scol];

    f32x4 acc[4][4];
#pragma unroll
    for (int i = 0; i < 4; i++)
#pragma unroll
        for (int j = 0; j < 4; j++) acc[i][j] = (f32x4){0.f, 0.f, 0.f, 0.f};

    float bv[4];
#pragma unroll
    for (int j = 0; j < 4; j++) bv[j] = bias[bn * 128 + wn * 64 + j * 16 + l15];

    for (int kk = 0; kk < 32; ++kk) {
        const float* xp = xg + kk * 32;
        const float* wp = wg + kk * 32;
        float4 a0 = *(const float4*)(xp + 0);
        float4 a1 = *(const float4*)(xp + 4);
        float4 a2 = *(const float4*)(xp + 8);
        float4 a3 = *(const float4*)(xp + 12);
        float4 b0 = *(const float4*)(wp + 0);
        float4 b1 = *(const float4*)(wp + 4);
        float4 b2 = *(const float4*)(wp + 8);
        float4 b3 = *(const float4*)(wp + 12);

        __syncthreads();
        *(bf16x8*)(asw + 0) = cvt8(a0, a1);
        *(bf16x8*)(asw + 8) = cvt8(a2, a3);
        *(bf16x8*)(bsw + 0) = cvt8(b0, b1);
        *(bf16x8*)(bsw + 8) = cvt8(b2, b3);
        __syncthreads();

        bf16x8 aF[4], bF[4];
#pragma unroll
        for (int s = 0; s < 4; s++) {
            aF[s] = *(const bf16x8*)&As[(wm * 64 + s * 16 + l15) * 40 + l4 * 8];
            bF[s] = *(const bf16x8*)&Bs[(wn * 64 + s * 16 + l15) * 40 + l4 * 8];
        }
#pragma unroll
        for (int i = 0; i < 4; i++)
#pragma unroll
            for (int j = 0; j < 4; j++)
                acc[i][j] = __builtin_amdgcn_mfma_f32_16x16x32_bf16(
                    aF[i], bF[j], acc[i][j], 0, 0, 0);
    }

#pragma unroll
    for (int i = 0; i < 4; i++) {
#pragma unroll
        for (int j = 0; j < 4; j++) {
            const int n     = bn * 128 + wn * 64 + j * 16 + l15;
            const int which = n >> 10;
            const int cc    = n & 1023;
            const int h     = cc >> 6, d = cc & 63;
            const float qs  = (which == 0) ? 0.125f : 1.0f;
#pragma unroll
            for (int r = 0; r < 4; r++) {
                const int m  = bm * 128 + wm * 64 + i * 16 + l4 * 4 + r;
                const int bi = m >> 11, t = m & 2047;
                const int bh = bi * NH + h;
                const float v = (acc[i][j][r] + bv[j]) * qs;
                size_t idx;
                if (which == 2)
                    idx = 2 * (size_t)WS_STRIDE + ((size_t)bh * D_HEAD + d) * T_SEQ + t;
                else
                    idx = (size_t)which * WS_STRIDE + ((size_t)bh * T_SEQ + t) * D_HEAD + d;
                ws[idx] = (__bf16)v;
            }
        }
    }
}

// ---------------------------------------------------------------------------
// Kernel 2: causal ReLU attention v5 — no atomics, 2 waves/SIMD. (unchanged)
// ---------------------------------------------------------------------------
__global__ __launch_bounds__(256) void attn(
    const bf16* __restrict__ ws, float* __restrict__ out)
{
    __shared__ bf16 Ks[128 * 64];    // [key][d], 8-chunk XOR swizzle
    __shared__ bf16 Vts[64 * 128];   // [d][key], 16-chunk XOR swizzle

    const int tid  = threadIdx.x;
    const int lane = tid & 63;
    const int w    = tid >> 6;           // 0..3
    const int l15  = lane & 15, qd = lane >> 4;

    const int bh = blockIdx.x & 31;      // XCD = blk&7 -> bh mod 8 affinity
    const int u  = blockIdx.x >> 5;      // 0..15
    const int qt = (u < 8) ? u : (23 - u);
    const int nj = qt + 1;
    const int qb = qt * 128;

    const bf16* qg = ws + (size_t)bh * (T_SEQ * D_HEAD);
    const bf16* kg = ws + WS_STRIDE + (size_t)bh * (T_SEQ * D_HEAD);
    const bf16* vt = ws + 2 * (size_t)WS_STRIDE + (size_t)bh * (D_HEAD * T_SEQ);
    const int b = bh >> 4, h = bh & 15;

    // staging lane constants
    const int ksub = lane >> 3;          // K: row-in-issue 0..7
    const int kc   = lane & 7;           // K: stored chunk
    const int vsub = qd;                 // V: row-in-issue 0..3
    const int vc   = l15;                // V: stored chunk

    // Q fragments (pre-scaled by 1/8), live across whole loop
    bf16x8 qF[2][2];
#pragma unroll
    for (int sm = 0; sm < 2; sm++)
#pragma unroll
        for (int dk = 0; dk < 2; dk++)
            qF[sm][dk] = *(const bf16x8*)(qg
                + (qb + w * 32 + sm * 16 + l15) * 64 + dk * 32 + qd * 8);

    f32x4 o[2][4];
#pragma unroll
    for (int sm = 0; sm < 2; sm++)
#pragma unroll
        for (int sd = 0; sd < 4; sd++) o[sm][sd] = (f32x4){0.f, 0.f, 0.f, 0.f};

    for (int jt = 0; jt < nj; ++jt) {
        __syncthreads();   // prev step's LDS fragment reads complete
        // ---- stage K tile [128][64]: 4 issues/wave (8 rows each) ----
#pragma unroll
        for (int e = 0; e < 4; e++) {
            const int rb = w * 32 + e * 8;
            gl_lds16(kg + (size_t)(jt * 128 + rb + ksub) * 64 + ((kc ^ ksub) * 8),
                     &Ks[rb * 64]);
        }
        // ---- stage V^T tile [64][128]: 4 issues/wave (4 rows each) ----
#pragma unroll
        for (int e = 0; e < 4; e++) {
            const int rb = w * 16 + e * 4;
            const int sw = (rb & 12) + vsub;   // == (row & 15) for this lane
            gl_lds16(vt + (size_t)(rb + vsub) * T_SEQ + jt * 128 + ((vc ^ sw) * 8),
                     &Vts[rb * 128]);
        }
        __syncthreads();   // drains vmcnt -> staging visible

        // ---- QK (permuted rows) + mask + pack, per kn ----
        const bool need_mask = (jt == nj - 1);
        unsigned PK[2][8][2];
#pragma unroll
        for (int kn = 0; kn < 8; kn++) {
            const int r7  = 4 * (kn & 1) + (l15 & 3);
            const int row = 32 * (kn >> 1) + 8 * (l15 >> 2) + r7;
            bf16x8 kf0 = *(const bf16x8*)&Ks[row * 64 + ((qd ^ r7) * 8)];
            bf16x8 kf1 = *(const bf16x8*)&Ks[row * 64 + (((4 + qd) ^ r7) * 8)];
            f32x4 s0 = {0.f, 0.f, 0.f, 0.f}, s1 = {0.f, 0.f, 0.f, 0.f};
            s0 = __builtin_amdgcn_mfma_f32_16x16x32_bf16(kf0, qF[0][0], s0, 0, 0, 0);
            s0 = __builtin_amdgcn_mfma_f32_16x16x32_bf16(kf1, qF[0][1], s0, 0, 0, 0);
            s1 = __builtin_amdgcn_mfma_f32_16x16x32_bf16(kf0, qF[1][0], s1, 0, 0, 0);
            s1 = __builtin_amdgcn_mfma_f32_16x16x32_bf16(kf1, qF[1][1], s1, 0, 0, 0);
            const int keyb = jt * 128 + 32 * (kn >> 1) + 8 * qd + 4 * (kn & 1);
#pragma unroll
            for (int sm = 0; sm < 2; sm++) {
                const f32x4 sv = sm ? s1 : s0;
                const int q = qb + w * 32 + sm * 16 + l15;
                float v[4];
#pragma unroll
                for (int r = 0; r < 4; r++) {
                    float val = fmaxf(sv[r], 0.f);
                    if (need_mask && q < keyb + r) val = 0.f;
                    v[r] = val;
                }
                PK[sm][kn][0] = pack_bf16(v[0], v[1]);
                PK[sm][kn][1] = pack_bf16(v[2], v[3]);
            }
        }

        // ---- PV: pF direct from this lane's PK dwords; vF from LDS ----
#pragma unroll
        for (int kk = 0; kk < 4; kk++) {
            bf16x8 pF[2];
#pragma unroll
            for (int sm = 0; sm < 2; sm++) {
                union { unsigned dw[4]; bf16x8 v; } uu;
                uu.dw[0] = PK[sm][2 * kk + 0][0];
                uu.dw[1] = PK[sm][2 * kk + 0][1];
                uu.dw[2] = PK[sm][2 * kk + 1][0];
                uu.dw[3] = PK[sm][2 * kk + 1][1];
                pF[sm] = uu.v;
            }
#pragma unroll
            for (int sd = 0; sd < 4; sd++) {
                bf16x8 vf = *(const bf16x8*)&Vts[(sd * 16 + l15) * 128
                                                 + (((kk * 4 + qd) ^ l15) * 8)];
                o[0][sd] = __builtin_amdgcn_mfma_f32_16x16x32_bf16(pF[0], vf, o[0][sd], 0, 0, 0);
                o[1][sd] = __builtin_amdgcn_mfma_f32_16x16x32_bf16(pF[1], vf, o[1][sd], 0, 0, 0);
            }
        }
    }

    // ---- plain-store O (exclusive q-row ownership) ----
#pragma unroll
    for (int sm = 0; sm < 2; sm++)
#pragma unroll
        for (int sd = 0; sd < 4; sd++) {
            const int d = sd * 16 + l15;
#pragma unroll
            for (int r = 0; r < 4; r++) {
                const int t = qb + w * 32 + sm * 16 + qd * 4 + r;
                out[((size_t)b * T_SEQ + t) * C_EMB + h * 64 + d] = o[sm][sd][r];
            }
        }
}

extern "C" void kernel_launch(void* const* d_in, const int* in_sizes, int n_in,
                              void* d_out, int out_size, void* d_ws, size_t ws_size,
                              hipStream_t stream) {
    const float* x    = (const float*)d_in[0];
    const float* W    = (const float*)d_in[1];
    const float* bias = (const float*)d_in[2];
    float* out        = (float*)d_out;
    bf16*  ws         = (bf16*)d_ws;

    if (ws_size >= WS_NEEDED) {
        bf16* xb = ws + 3 * (size_t)WS_STRIDE;
        bf16* wb = xb + XN;
        cvt_bf16<<<dim3(CVT_GRID), dim3(256), 0, stream>>>(x, W, xb, wb);
        qkv_gemm3<<<dim3(192), dim3(512), 0, stream>>>(xb, wb, bias, ws);
    } else {
        qkv_gemm<<<dim3(768), dim3(256), 0, stream>>>(x, W, bias, ws);
    }
    attn<<<dim3(512), dim3(256), 0, stream>>>(ws, out);
}

// Round 2
// 146.685 us; speedup vs baseline: 1.0655x; 1.0097x over previous
//
#include <hip/hip_runtime.h>

typedef __bf16 bf16;
typedef __bf16 bf16x8 __attribute__((ext_vector_type(8)));
typedef float  f32x4  __attribute__((ext_vector_type(4)));

#define T_SEQ   2048
#define D_HEAD  64
#define NH      16
#define BH      32
#define C_EMB   1024
#define WS_STRIDE (BH * T_SEQ * D_HEAD)   // 4,194,304 elems per plane
#define XN (4096 * 1024)
#define WN (3072 * 1024)
#define WS_NEEDED ((size_t)(3 * WS_STRIDE + XN + WN) * 2)
#define CVT_GRID 3584

__device__ __forceinline__ bf16x8 cvt8(float4 a, float4 b) {
    bf16x8 r;
    r[0] = (__bf16)a.x; r[1] = (__bf16)a.y; r[2] = (__bf16)a.z; r[3] = (__bf16)a.w;
    r[4] = (__bf16)b.x; r[5] = (__bf16)b.y; r[6] = (__bf16)b.z; r[7] = (__bf16)b.w;
    return r;
}

__device__ __forceinline__ void gl_lds16(const bf16* g, bf16* l) {
    __builtin_amdgcn_global_load_lds(
        (const __attribute__((address_space(1))) unsigned int*)g,
        (__attribute__((address_space(3))) unsigned int*)l,
        16, 0, 0);
}

__device__ __forceinline__ unsigned pack_bf16(float a, float b) {
    union { __bf16 h[2]; unsigned u; } pk;
    pk.h[0] = (__bf16)a; pk.h[1] = (__bf16)b;
    return pk.u;
}

// ---------------------------------------------------------------------------
// Kernel 0: fp32 -> bf16 convert of x and W.
// ---------------------------------------------------------------------------
__global__ __launch_bounds__(256) void cvt_bf16(
    const float* __restrict__ x, const float* __restrict__ W,
    bf16* __restrict__ xb, bf16* __restrict__ wb)
{
    const int t = blockIdx.x * 256 + threadIdx.x;   // 917504 threads
    const float* src; bf16* dst; int base;
    if (t < XN / 8) { src = x; dst = xb; base = t * 8; }
    else           { src = W; dst = wb; base = (t - XN / 8) * 8; }
    float4 a = *(const float4*)(src + base);
    float4 b = *(const float4*)(src + base + 4);
    *(bf16x8*)(dst + base) = cvt8(a, b);
}

// ---------------------------------------------------------------------------
// Kernel 1: qkv = xb @ wb^T + b.  256x256 tile, BK=64, 8 waves (2Mx4N),
// 8-phase double-buffered pipeline (T3+T4): each K-tile = 4 quadrant phases
// of 16 MFMA; staging global_load_lds lands in quarter-regions that died in
// an earlier phase; s_waitcnt vmcnt(8) once per K-tile (never 0 in loop).
// T2 XOR-swizzled staging (pre-swizzled global source, linear LDS dest),
// T5 setprio around MFMA clusters, T1 bijective XCD swizzle (192%8==0).
// ---------------------------------------------------------------------------
#define LDA(d, qi) {                                                          \
    const bf16* abase_ = Sh + (d)*16384 + (qi)*8192 + (wm*64 + l15)*64;       \
    _Pragma("unroll")                                                         \
    for (int ii_ = 0; ii_ < 4; ii_++) {                                       \
        _Pragma("unroll")                                                     \
        for (int dk_ = 0; dk_ < 2; dk_++)                                     \
            aF[ii_][dk_] = *(const bf16x8*)(abase_ + ii_*1024                 \
                                            + (((dk_*4 + l4) ^ k7) * 8));     \
    }                                                                         \
}

#define LDB(d, qj, bFv) {                                                     \
    const bf16* bbase_ = Sh + 32768 + (d)*16384 + (qj)*8192                   \
                         + (wn*32 + l15)*64;                                  \
    _Pragma("unroll")                                                         \
    for (int jj_ = 0; jj_ < 2; jj_++) {                                       \
        _Pragma("unroll")                                                     \
        for (int dk_ = 0; dk_ < 2; dk_++)                                     \
            bFv[jj_][dk_] = *(const bf16x8*)(bbase_ + jj_*1024                \
                                             + (((dk_*4 + l4) ^ k7) * 8));    \
    }                                                                         \
}

#define STA(d, qi, s, ko) gl_lds16(                                           \
    aSrc + (size_t)((qi)*64 + (s)*128) * 1024 + (ko),                         \
    Sh + (d)*16384 + (qi)*8192 + (s)*4096 + w*512)

#define STB(d, qj, s, ko) gl_lds16(                                           \
    bSrc + (size_t)((s)*128 + (qj)*32) * 1024 + (ko),                         \
    Sh + 32768 + (d)*16384 + (qj)*8192 + (s)*4096 + w*512)

#define MMAQ(qi, qj, bFv) {                                                   \
    __builtin_amdgcn_s_setprio(1);                                            \
    _Pragma("unroll")                                                         \
    for (int dk_ = 0; dk_ < 2; dk_++) {                                       \
        _Pragma("unroll")                                                     \
        for (int ii_ = 0; ii_ < 4; ii_++) {                                   \
            _Pragma("unroll")                                                 \
            for (int jj_ = 0; jj_ < 2; jj_++)                                 \
                acc[(qi)*4 + ii_][(qj)*2 + jj_] =                             \
                    __builtin_amdgcn_mfma_f32_16x16x32_bf16(                  \
                        aF[ii_][dk_], bFv[jj_][dk_],                          \
                        acc[(qi)*4 + ii_][(qj)*2 + jj_], 0, 0, 0);            \
        }                                                                     \
    }                                                                         \
    __builtin_amdgcn_s_setprio(0);                                            \
}

#define BAR   __builtin_amdgcn_s_barrier()
#define LGKM0 asm volatile("s_waitcnt lgkmcnt(0)" ::: "memory")

#define HALF(d, sk)                                                           \
    /* P0 */                                                                  \
    LDA(d, 0) LDB(d, 0, bF0)                                                  \
    BAR; LGKM0;                                                               \
    MMAQ(0, 0, bF0)                                                           \
    BAR;                                                                      \
    /* P1 */                                                                  \
    LDB(d, 1, bF1)                                                            \
    STA(d, 0, 0, sk); STA(d, 0, 1, sk); STB(d, 0, 0, sk); STB(d, 0, 1, sk);   \
    BAR; LGKM0;                                                               \
    MMAQ(0, 1, bF1)                                                           \
    BAR;                                                                      \
    /* P2 */                                                                  \
    LDA(d, 1)                                                                 \
    STB(d, 1, 0, sk); STB(d, 1, 1, sk);                                       \
    BAR; LGKM0;                                                               \
    MMAQ(1, 0, bF0)                                                           \
    BAR;                                                                      \
    /* P3 */                                                                  \
    STA(d, 1, 0, sk); STA(d, 1, 1, sk);                                       \
    BAR;                                                                      \
    MMAQ(1, 1, bF1)                                                           \
    asm volatile("s_waitcnt vmcnt(8)" ::: "memory");                          \
    BAR;

__global__ __launch_bounds__(512, 2) void qkv_gemm3(
    const bf16* __restrict__ xb, const bf16* __restrict__ wb,
    const float* __restrict__ bias, bf16* __restrict__ ws)
{
    __shared__ bf16 Sh[65536];   // 128 KiB

    const int tid  = threadIdx.x;
    const int lane = tid & 63;
    const int w    = tid >> 6;            // 0..7
    const int wm   = w >> 2, wn = w & 3;  // 2x4 wave grid
    const int l15  = lane & 15, l4 = lane >> 4;
    const int k7   = l15 & 7;
    const int l8   = lane >> 3;           // staging row-in-wave
    const int csw  = (lane & 7) ^ l8;     // pre-swizzled source chunk

    const int swz = (blockIdx.x & 7) * 24 + (blockIdx.x >> 3);  // T1, bijective
    const int bm  = swz / 12, bn = swz % 12;

    const bf16* aSrc = xb + (size_t)(bm * 256 + w * 8 + l8) * 1024 + csw * 8;
    const bf16* bSrc = wb + (size_t)(bn * 256 + (w >> 2) * 64 + (w & 3) * 8 + l8) * 1024
                          + csw * 8;

    f32x4 acc[8][4];
#pragma unroll
    for (int i = 0; i < 8; i++)
#pragma unroll
        for (int j = 0; j < 4; j++) acc[i][j] = (f32x4){0.f, 0.f, 0.f, 0.f};

    bf16x8 aF[4][2], bF0[2][2], bF1[2][2];

    // ---- prologue: stage tile0 -> buf0, tile1 -> buf1 (8 loads each) ----
    STA(0,0,0,0);  STA(0,0,1,0);  STB(0,0,0,0);  STB(0,0,1,0);
    STB(0,1,0,0);  STB(0,1,1,0);  STA(0,1,0,0);  STA(0,1,1,0);
    STA(1,0,0,64); STA(1,0,1,64); STB(1,0,0,64); STB(1,0,1,64);
    STB(1,1,0,64); STB(1,1,1,64); STA(1,1,0,64); STA(1,1,1,64);
    asm volatile("s_waitcnt vmcnt(8)" ::: "memory");   // tile0 landed
    BAR;

    // ---- main loop: 8 iterations x 2 K-tiles (K=1024, BK=64) ----
    for (int it = 0; it < 8; ++it) {
        const int sk0 = (it < 7 ? (2 * it + 2) : 15) * 64;  // clamp: re-stage
        const int sk1 = (it < 7 ? (2 * it + 3) : 15) * 64;  // tile15 harmlessly
        HALF(0, sk0)
        HALF(1, sk1)
    }
    asm volatile("s_waitcnt vmcnt(0)" ::: "memory");   // drain garbage stages
    BAR;                                               // LDS now reusable

    // ---- epilogue: +bias (+0.125 for q); per-wave LDS transpose ----
    float bv[4];
#pragma unroll
    for (int j = 0; j < 4; j++) bv[j] = bias[bn * 256 + wn * 64 + j * 16 + l15];

    const int which = bn >> 2;             // 0=q, 1=k, 2=v (block-uniform)
    const int h     = (bn & 3) * 4 + wn;   // head (wave-uniform)
    const int bi    = bm >> 3;             // batch (block-uniform)
    const int tBase = (bm & 7) * 256 + wm * 128;
    const float qs  = (which == 0) ? 0.125f : 1.0f;
    bf16* Wl = Sh + w * 8192;              // private 16 KiB slice

    if (which < 2) {
#pragma unroll
        for (int i = 0; i < 8; i++)
#pragma unroll
            for (int j = 0; j < 4; j++)
#pragma unroll
                for (int r = 0; r < 4; r++) {
                    const int lm = i * 16 + l4 * 4 + r;     // 0..127 (t-local)
                    const int dd = j * 16 + l15;            // 0..63  (d)
                    const int cp = (dd >> 3) ^ (lm & 7);
                    Wl[lm * 64 + cp * 8 + (dd & 7)] =
                        (__bf16)((acc[i][j][r] + bv[j]) * qs);
                }
#pragma unroll
        for (int e = 0; e < 16; e++) {
            const int lm = e * 8 + l8;
            const int c  = lane & 7;
            bf16x8 v8 = *(const bf16x8*)&Wl[lm * 64 + ((c ^ (lm & 7)) * 8)];
            const int t = tBase + lm;
            *(bf16x8*)&ws[(size_t)which * WS_STRIDE
                          + ((size_t)(bi * NH + h) * T_SEQ + t) * D_HEAD + c * 8] = v8;
        }
    } else {
#pragma unroll
        for (int i = 0; i < 8; i++)
#pragma unroll
            for (int j = 0; j < 4; j++) {
                const int dd = j * 16 + l15;
#pragma unroll
                for (int p = 0; p < 2; p++) {
                    const int lm = i * 16 + l4 * 4 + 2 * p;
                    const int ch = lm >> 3;                 // 0..15
                    const int cp = (ch & 8) | ((ch & 7) ^ (dd & 7));
                    *(unsigned*)&Wl[dd * 128 + cp * 8 + (lm & 7)] =
                        pack_bf16(acc[i][j][2 * p] + bv[j],
                                  acc[i][j][2 * p + 1] + bv[j]);
                }
            }
        bf16* vt = ws + 2 * (size_t)WS_STRIDE;
#pragma unroll
        for (int e = 0; e < 16; e++) {
            const int dd = e * 4 + l4;
            const int c  = l15;
            const int cp = (c & 8) | ((c & 7) ^ (dd & 7));
            bf16x8 v8 = *(const bf16x8*)&Wl[dd * 128 + cp * 8];
            *(bf16x8*)&vt[((size_t)(bi * NH + h) * D_HEAD + dd) * T_SEQ
                          + tBase + c * 8] = v8;
        }
    }
}

// ---------------------------------------------------------------------------
// Kernel 1 fallback (ws too small): register-convert GEMM, scalar epilogue.
// ---------------------------------------------------------------------------
__global__ __launch_bounds__(256) void qkv_gemm(
    const float* __restrict__ x, const float* __restrict__ W,
    const float* __restrict__ bias, bf16* __restrict__ ws)
{
    __shared__ bf16 As[128 * 40];
    __shared__ bf16 Bs[128 * 40];

    const int tid  = threadIdx.x;
    const int lane = tid & 63;
    const int w    = tid >> 6;
    const int wm   = w >> 1, wn = w & 1;
    const int l15  = lane & 15, l4 = lane >> 4;
    const int bm   = blockIdx.x / 24, bn = blockIdx.x % 24;

    const int srow = tid >> 1;
    const int scol = (tid & 1) * 16;
    const float* xg = x + (size_t)(bm * 128 + srow) * 1024 + scol;
    const float* wg = W + (size_t)(bn * 128 + srow) * 1024 + scol;
    bf16* asw = &As[srow * 40 + scol];
    bf16* bsw = &Bs[srow * 40 + scol];

    f32x4 acc[4][4];
#pragma unroll
    for (int i = 0; i < 4; i++)
#pragma unroll
        for (int j = 0; j < 4; j++) acc[i][j] = (f32x4){0.f, 0.f, 0.f, 0.f};

    float bv[4];
#pragma unroll
    for (int j = 0; j < 4; j++) bv[j] = bias[bn * 128 + wn * 64 + j * 16 + l15];

    for (int kk = 0; kk < 32; ++kk) {
        const float* xp = xg + kk * 32;
        const float* wp = wg + kk * 32;
        float4 a0 = *(const float4*)(xp + 0);
        float4 a1 = *(const float4*)(xp + 4);
        float4 a2 = *(const float4*)(xp + 8);
        float4 a3 = *(const float4*)(xp + 12);
        float4 b0 = *(const float4*)(wp + 0);
        float4 b1 = *(const float4*)(wp + 4);
        float4 b2 = *(const float4*)(wp + 8);
        float4 b3 = *(const float4*)(wp + 12);

        __syncthreads();
        *(bf16x8*)(asw + 0) = cvt8(a0, a1);
        *(bf16x8*)(asw + 8) = cvt8(a2, a3);
        *(bf16x8*)(bsw + 0) = cvt8(b0, b1);
        *(bf16x8*)(bsw + 8) = cvt8(b2, b3);
        __syncthreads();

        bf16x8 aF[4], bF[4];
#pragma unroll
        for (int s = 0; s < 4; s++) {
            aF[s] = *(const bf16x8*)&As[(wm * 64 + s * 16 + l15) * 40 + l4 * 8];
            bF[s] = *(const bf16x8*)&Bs[(wn * 64 + s * 16 + l15) * 40 + l4 * 8];
        }
#pragma unroll
        for (int i = 0; i < 4; i++)
#pragma unroll
            for (int j = 0; j < 4; j++)
                acc[i][j] = __builtin_amdgcn_mfma_f32_16x16x32_bf16(
                    aF[i], bF[j], acc[i][j], 0, 0, 0);
    }

#pragma unroll
    for (int i = 0; i < 4; i++) {
#pragma unroll
        for (int j = 0; j < 4; j++) {
            const int n     = bn * 128 + wn * 64 + j * 16 + l15;
            const int which = n >> 10;
            const int cc    = n & 1023;
            const int h     = cc >> 6, d = cc & 63;
            const float qs  = (which == 0) ? 0.125f : 1.0f;
#pragma unroll
            for (int r = 0; r < 4; r++) {
                const int m  = bm * 128 + wm * 64 + i * 16 + l4 * 4 + r;
                const int bi = m >> 11, t = m & 2047;
                const int bh = bi * NH + h;
                const float v = (acc[i][j][r] + bv[j]) * qs;
                size_t idx;
                if (which == 2)
                    idx = 2 * (size_t)WS_STRIDE + ((size_t)bh * D_HEAD + d) * T_SEQ + t;
                else
                    idx = (size_t)which * WS_STRIDE + ((size_t)bh * T_SEQ + t) * D_HEAD + d;
                ws[idx] = (__bf16)v;
            }
        }
    }
}

// ---------------------------------------------------------------------------
// Kernel 2: causal ReLU attention v6 — double-buffered K/V pipeline.
// 512 blocks x 256 threads (4 waves). Exclusive q-row ownership, plain
// stores. Per jt step: issue next tile's 8 global_load_lds (T14 issue-early),
// s_waitcnt vmcnt(8) counted (T4 — next tile stays in flight across the
// barrier; never drain to 0 in the loop), raw s_barrier, compute, trailing
// barrier (WAR: stage at jt+1 overwrites the buffer read at jt).
// Causal-mask VALU hoisted under wave-uniform need_mask branch.
// T5 setprio around QK/PV MFMA clusters. LDS 64 KiB -> still 2 blocks/CU.
// ---------------------------------------------------------------------------
#define ASTAGE(jt_, p_) {                                                     \
    _Pragma("unroll")                                                         \
    for (int e_ = 0; e_ < 4; e_++) {                                          \
        const int rb_ = w * 32 + e_ * 8;                                      \
        gl_lds16(kg + (size_t)((jt_) * 128 + rb_ + ksub) * 64                 \
                    + ((kc ^ ksub) * 8),                                      \
                 &Ks[p_][rb_ * 64]);                                          \
    }                                                                         \
    _Pragma("unroll")                                                         \
    for (int e_ = 0; e_ < 4; e_++) {                                          \
        const int rb_ = w * 16 + e_ * 4;                                      \
        const int sw_ = (rb_ & 12) + vsub;                                    \
        gl_lds16(vt + (size_t)(rb_ + vsub) * T_SEQ + (jt_) * 128              \
                    + ((vc ^ sw_) * 8),                                       \
                 &Vts[p_][rb_ * 128]);                                        \
    }                                                                         \
}

__global__ __launch_bounds__(256) void attn(
    const bf16* __restrict__ ws, float* __restrict__ out)
{
    __shared__ bf16 Ks[2][128 * 64];    // [key][d], 8-chunk XOR swizzle
    __shared__ bf16 Vts[2][64 * 128];   // [d][key], 16-chunk XOR swizzle

    const int tid  = threadIdx.x;
    const int lane = tid & 63;
    const int w    = tid >> 6;           // 0..3
    const int l15  = lane & 15, qd = lane >> 4;

    const int bh = blockIdx.x & 31;      // XCD = blk&7 -> bh mod 8 affinity
    const int u  = blockIdx.x >> 5;      // 0..15
    const int qt = (u < 8) ? u : (23 - u);
    const int nj = qt + 1;
    const int qb = qt * 128;

    const bf16* qg = ws + (size_t)bh * (T_SEQ * D_HEAD);
    const bf16* kg = ws + WS_STRIDE + (size_t)bh * (T_SEQ * D_HEAD);
    const bf16* vt = ws + 2 * (size_t)WS_STRIDE + (size_t)bh * (D_HEAD * T_SEQ);
    const int b = bh >> 4, h = bh & 15;

    // staging lane constants
    const int ksub = lane >> 3;          // K: row-in-issue 0..7
    const int kc   = lane & 7;           // K: stored chunk
    const int vsub = qd;                 // V: row-in-issue 0..3
    const int vc   = l15;                // V: stored chunk

    // Q fragments (pre-scaled by 1/8), live across whole loop
    bf16x8 qF[2][2];
#pragma unroll
    for (int sm = 0; sm < 2; sm++)
#pragma unroll
        for (int dk = 0; dk < 2; dk++)
            qF[sm][dk] = *(const bf16x8*)(qg
                + (qb + w * 32 + sm * 16 + l15) * 64 + dk * 32 + qd * 8);

    f32x4 o[2][4];
#pragma unroll
    for (int sm = 0; sm < 2; sm++)
#pragma unroll
        for (int sd = 0; sd < 4; sd++) o[sm][sd] = (f32x4){0.f, 0.f, 0.f, 0.f};

    // ---- prologue: stage tile 0 into buffer 0 ----
    ASTAGE(0, 0);

    for (int jt = 0; jt < nj; ++jt) {
        const int p = jt & 1;
        // issue next tile early (T14); counted wait keeps it in flight (T4)
        if (jt + 1 < nj) {
            ASTAGE(jt + 1, p ^ 1);
            asm volatile("s_waitcnt vmcnt(8)" ::: "memory");  // tile jt landed
        } else {
            asm volatile("s_waitcnt vmcnt(0)" ::: "memory");
        }
        BAR;   // all waves' staging for tile jt visible

        const bf16* Kp = Ks[p];
        const bf16* Vp = Vts[p];

        // ---- QK (permuted rows) + mask + pack, per kn ----
        const bool need_mask = (jt == nj - 1);
        unsigned PK[2][8][2];
#pragma unroll
        for (int kn = 0; kn < 8; kn++) {
            const int r7  = 4 * (kn & 1) + (l15 & 3);
            const int row = 32 * (kn >> 1) + 8 * (l15 >> 2) + r7;
            bf16x8 kf0 = *(const bf16x8*)&Kp[row * 64 + ((qd ^ r7) * 8)];
            bf16x8 kf1 = *(const bf16x8*)&Kp[row * 64 + (((4 + qd) ^ r7) * 8)];
            f32x4 s0 = {0.f, 0.f, 0.f, 0.f}, s1 = {0.f, 0.f, 0.f, 0.f};
            __builtin_amdgcn_s_setprio(1);
            s0 = __builtin_amdgcn_mfma_f32_16x16x32_bf16(kf0, qF[0][0], s0, 0, 0, 0);
            s0 = __builtin_amdgcn_mfma_f32_16x16x32_bf16(kf1, qF[0][1], s0, 0, 0, 0);
            s1 = __builtin_amdgcn_mfma_f32_16x16x32_bf16(kf0, qF[1][0], s1, 0, 0, 0);
            s1 = __builtin_amdgcn_mfma_f32_16x16x32_bf16(kf1, qF[1][1], s1, 0, 0, 0);
            __builtin_amdgcn_s_setprio(0);
            const int keyb = jt * 128 + 32 * (kn >> 1) + 8 * qd + 4 * (kn & 1);
#pragma unroll
            for (int sm = 0; sm < 2; sm++) {
                const f32x4 sv = sm ? s1 : s0;
                float v[4];
#pragma unroll
                for (int r = 0; r < 4; r++) v[r] = fmaxf(sv[r], 0.f);
                if (need_mask) {   // wave-uniform: VALU only on last step
                    const int q = qb + w * 32 + sm * 16 + l15;
#pragma unroll
                    for (int r = 0; r < 4; r++)
                        if (q < keyb + r) v[r] = 0.f;
                }
                PK[sm][kn][0] = pack_bf16(v[0], v[1]);
                PK[sm][kn][1] = pack_bf16(v[2], v[3]);
            }
        }

        // ---- PV: pF direct from this lane's PK dwords; vF from LDS ----
#pragma unroll
        for (int kk = 0; kk < 4; kk++) {
            bf16x8 pF[2];
#pragma unroll
            for (int sm = 0; sm < 2; sm++) {
                union { unsigned dw[4]; bf16x8 v; } uu;
                uu.dw[0] = PK[sm][2 * kk + 0][0];
                uu.dw[1] = PK[sm][2 * kk + 0][1];
                uu.dw[2] = PK[sm][2 * kk + 1][0];
                uu.dw[3] = PK[sm][2 * kk + 1][1];
                pF[sm] = uu.v;
            }
            __builtin_amdgcn_s_setprio(1);
#pragma unroll
            for (int sd = 0; sd < 4; sd++) {
                bf16x8 vf = *(const bf16x8*)&Vp[(sd * 16 + l15) * 128
                                                + (((kk * 4 + qd) ^ l15) * 8)];
                o[0][sd] = __builtin_amdgcn_mfma_f32_16x16x32_bf16(pF[0], vf, o[0][sd], 0, 0, 0);
                o[1][sd] = __builtin_amdgcn_mfma_f32_16x16x32_bf16(pF[1], vf, o[1][sd], 0, 0, 0);
            }
            __builtin_amdgcn_s_setprio(0);
        }

        BAR;   // WAR: next iteration's stage overwrites the buffer just read
    }

    // ---- plain-store O (exclusive q-row ownership) ----
#pragma unroll
    for (int sm = 0; sm < 2; sm++)
#pragma unroll
        for (int sd = 0; sd < 4; sd++) {
            const int d = sd * 16 + l15;
#pragma unroll
            for (int r = 0; r < 4; r++) {
                const int t = qb + w * 32 + sm * 16 + qd * 4 + r;
                out[((size_t)b * T_SEQ + t) * C_EMB + h * 64 + d] = o[sm][sd][r];
            }
        }
}

extern "C" void kernel_launch(void* const* d_in, const int* in_sizes, int n_in,
                              void* d_out, int out_size, void* d_ws, size_t ws_size,
                              hipStream_t stream) {
    const float* x    = (const float*)d_in[0];
    const float* W    = (const float*)d_in[1];
    const float* bias = (const float*)d_in[2];
    float* out        = (float*)d_out;
    bf16*  ws         = (bf16*)d_ws;

    if (ws_size >= WS_NEEDED) {
        bf16* xb = ws + 3 * (size_t)WS_STRIDE;
        bf16* wb = xb + XN;
        cvt_bf16<<<dim3(CVT_GRID), dim3(256), 0, stream>>>(x, W, xb, wb);
        qkv_gemm3<<<dim3(192), dim3(512), 0, stream>>>(xb, wb, bias, ws);
    } else {
        qkv_gemm<<<dim3(768), dim3(256), 0, stream>>>(x, W, bias, ws);
    }
    attn<<<dim3(512), dim3(256), 0, stream>>>(ws, out);
}